// Round 3
// baseline (2429.553 us; speedup 1.0000x reference)
//
#include <hip/hip_runtime.h>
#include <hip/hip_bf16.h>

typedef unsigned short u16;
typedef unsigned int   u32;

#define V_N 100000
#define E_N 1600000
#define NIN 128
#define EIN 50
#define HH  50

__device__ __forceinline__ float bf2f(u16 u) {
    union { u32 i; float f; } v; v.i = ((u32)u) << 16; return v.f;
}
__device__ __forceinline__ u16 f2bf(float f) {
    union { float f; u32 i; } v; v.f = f;
    u32 x = v.i;
    return (u16)((x + 0x7fffu + ((x >> 16) & 1u)) >> 16);
}

// ---------------------------------------------------------------------------
// Kernel A: left = nf @ w_l + b_l, right = nf @ w_r + b_r  (bf16 out to ws)
// 64 rows/block. ws footprint: 2 x 10 MB only.
// ---------------------------------------------------------------------------
__global__ __launch_bounds__(256) void k_lr(
    const float* __restrict__ nf,
    const float* __restrict__ w1, const float* __restrict__ b1,
    const float* __restrict__ w2, const float* __restrict__ b2,
    u16* __restrict__ left, u16* __restrict__ right)
{
    __shared__ u16 sw[2 * NIN * HH];   // 25600 B
    __shared__ u16 sx[64 * NIN];       // 16384 B
    __shared__ float sb[2 * HH];

    const int tid = threadIdx.x;
    for (int i = tid; i < NIN * HH; i += 256) {
        sw[i]          = f2bf(w1[i]);
        sw[NIN*HH + i] = f2bf(w2[i]);
    }
    if (tid < HH) {
        sb[tid]      = b1[tid];
        sb[HH + tid] = b2[tid];
    }
    const int row0 = blockIdx.x * 64;
    const float4* nf4 = (const float4*)nf;
    const int base4 = row0 * (NIN / 4);
    for (int i = tid; i < 64 * NIN / 4; i += 256) {
        float4 v = make_float4(0.f, 0.f, 0.f, 0.f);
        if (base4 + i < V_N * NIN / 4) v = nf4[base4 + i];
        ushort4 p;
        p.x = f2bf(v.x); p.y = f2bf(v.y); p.z = f2bf(v.z); p.w = f2bf(v.w);
        ((ushort4*)sx)[i] = p;
    }
    __syncthreads();

    for (int t = tid; t < 8 * HH; t += 256) {   // 8 row-tiles x 50 cols
        const int rt = t / HH, c = t - rt * HH;
        float a1[8], a2[8];
        #pragma unroll
        for (int j = 0; j < 8; ++j) { a1[j] = sb[c]; a2[j] = sb[HH+c]; }
        const u16* xr = &sx[rt * 8 * NIN];
        for (int k = 0; k < NIN; ++k) {
            const float wv1 = bf2f(sw[k*HH + c]);
            const float wv2 = bf2f(sw[NIN*HH + k*HH + c]);
            #pragma unroll
            for (int j = 0; j < 8; ++j) {
                const float x = bf2f(xr[j*NIN + k]);
                a1[j] = fmaf(x, wv1, a1[j]);
                a2[j] = fmaf(x, wv2, a2[j]);
            }
        }
        #pragma unroll
        for (int j = 0; j < 8; ++j) {
            const int r = row0 + rt*8 + j;
            if (r < V_N) {
                left [(size_t)r*HH + c] = f2bf(a1[j]);
                right[(size_t)r*HH + c] = f2bf(a2[j]);
            }
        }
    }
}

// ---------------------------------------------------------------------------
// Kernel B: per 64 edges:
//   stage1: e2n=relu(ef@wA+bA) -> atomicAdd(edge_node_acc[dst])  (acc = d_out node region)
//           third=relu(ef@wB+bB); first/second from left/right gathers
//           -> sint[e][0..149] (bf16)
//   stage2: new_edge = relu(sint @ wU + bU)  -> fp32 out
// ---------------------------------------------------------------------------
__global__ __launch_bounds__(256) void k_edge(
    const float* __restrict__ ef,
    const int* __restrict__ src, const int* __restrict__ dst,
    const float* __restrict__ wA, const float* __restrict__ bA,
    const float* __restrict__ wB, const float* __restrict__ bB,
    const float* __restrict__ wU, const float* __restrict__ bU,
    const u16* __restrict__ left, const u16* __restrict__ right,
    float* __restrict__ edge_node_acc,
    float* __restrict__ out_edge)
{
    __shared__ u16 swA[EIN*HH];      // 5000 B
    __shared__ u16 swB[EIN*HH];      // 5000 B
    __shared__ u16 swU[3*HH*HH];     // 15000 B
    __shared__ float sb[3*HH];
    __shared__ u16 sef[64*EIN];      // 6400 B
    __shared__ u16 sint[64*150];     // 19200 B
    __shared__ int ssrc[64], sdst[64];

    const int tid = threadIdx.x;
    for (int i = tid; i < EIN*HH; i += 256) { swA[i] = f2bf(wA[i]); swB[i] = f2bf(wB[i]); }
    for (int i = tid; i < 3*HH*HH; i += 256) swU[i] = f2bf(wU[i]);
    if (tid < HH) {
        sb[tid]        = bA[tid];
        sb[HH + tid]   = bB[tid];
        sb[2*HH + tid] = bU[tid];
    }
    const int e0 = blockIdx.x * 64;   // E_N = 64 * 25000 exactly
    const float4* ef4 = (const float4*)(ef + (size_t)e0 * EIN);
    for (int i = tid; i < 64*EIN/4; i += 256) {
        float4 v = ef4[i];
        ushort4 p;
        p.x = f2bf(v.x); p.y = f2bf(v.y); p.z = f2bf(v.z); p.w = f2bf(v.w);
        ((ushort4*)sef)[i] = p;
    }
    if (tid < 64) { ssrc[tid] = src[e0+tid]; sdst[tid] = dst[e0+tid]; }
    __syncthreads();

    // stage 1: 16 edge-tiles (4 edges each) x 50 cols = 800 items
    for (int t = tid; t < 16 * HH; t += 256) {
        const int et = t / HH, c = t - et * HH;
        const int e = et * 4;
        float aA[4], aB[4];
        #pragma unroll
        for (int j = 0; j < 4; ++j) { aA[j] = sb[c]; aB[j] = sb[HH+c]; }
        for (int k = 0; k < EIN; ++k) {
            const float wa = bf2f(swA[k*HH + c]);
            const float wb = bf2f(swB[k*HH + c]);
            #pragma unroll
            for (int j = 0; j < 4; ++j) {
                const float x = bf2f(sef[(e+j)*EIN + k]);
                aA[j] = fmaf(x, wa, aA[j]);
                aB[j] = fmaf(x, wb, aB[j]);
            }
        }
        #pragma unroll
        for (int j = 0; j < 4; ++j) {
            const int s = ssrc[e+j], d = sdst[e+j];
            atomicAdd(&edge_node_acc[(size_t)d*HH + c], fmaxf(aA[j], 0.f));
            sint[(e+j)*150 + 100 + c] = f2bf(fmaxf(aB[j], 0.f));
            const float ls  = bf2f(left [(size_t)s*HH + c]);
            const float rd_ = bf2f(right[(size_t)d*HH + c]);
            const float rs  = bf2f(right[(size_t)s*HH + c]);
            const float ld  = bf2f(left [(size_t)d*HH + c]);
            sint[(e+j)*150 + c]      = f2bf(fmaxf(ls + rd_, 0.f));
            sint[(e+j)*150 + 50 + c] = f2bf(fmaxf(rs + ld, 0.f));
        }
    }
    __syncthreads();

    // stage 2: 16 edge-tiles x 25 col-pairs = 400 items
    for (int t = tid; t < 16 * 25; t += 256) {
        const int et = t / 25, ct = t - et * 25;
        const int e = et * 4, c = ct * 2;
        float acc[4][2];
        #pragma unroll
        for (int j = 0; j < 4; ++j) { acc[j][0] = sb[2*HH+c]; acc[j][1] = sb[2*HH+c+1]; }
        for (int k = 0; k < 150; ++k) {
            const float w0 = bf2f(swU[k*HH + c]);
            const float w1 = bf2f(swU[k*HH + c + 1]);
            #pragma unroll
            for (int j = 0; j < 4; ++j) {
                const float x = bf2f(sint[(e+j)*150 + k]);
                acc[j][0] = fmaf(x, w0, acc[j][0]);
                acc[j][1] = fmaf(x, w1, acc[j][1]);
            }
        }
        #pragma unroll
        for (int j = 0; j < 4; ++j) {
            const size_t o = (size_t)(e0 + e + j) * HH + c;   // c even -> 8B aligned
            float2 v;
            v.x = fmaxf(acc[j][0], 0.f);
            v.y = fmaxf(acc[j][1], 0.f);
            *(float2*)(out_edge + o) = v;
        }
    }
}

// ---------------------------------------------------------------------------
// Kernel C: node_node = relu(nf @ w_n2n + b) recomputed in-block;
// new_node = relu(concat(node_node, edge_node) @ wU + bU) overwrites the
// edge_node accumulator region (each block touches only its own 64 rows).
// ---------------------------------------------------------------------------
__global__ __launch_bounds__(256) void k_node_upd(
    const float* __restrict__ nf,
    const float* __restrict__ w_n2n, const float* __restrict__ b_n2n,
    const float* __restrict__ wU, const float* __restrict__ bU,
    float* __restrict__ node_out /* also edge_node accumulator */)
{
    __shared__ u16 swn[NIN*HH];    // 12800 B
    __shared__ u16 swu[2*HH*HH];   // 10000 B
    __shared__ float sb[2*HH];     // 400 B
    __shared__ u16 sx[64*NIN];     // 16384 B
    __shared__ u16 snn[64*HH];     // 6400 B
    __shared__ float sen[64*HH];   // 12800 B  -> total 58784 B

    const int tid = threadIdx.x;
    for (int i = tid; i < NIN*HH; i += 256) swn[i] = f2bf(w_n2n[i]);
    for (int i = tid; i < 2*HH*HH; i += 256) swu[i] = f2bf(wU[i]);
    if (tid < HH) { sb[tid] = b_n2n[tid]; sb[HH + tid] = bU[tid]; }

    const int n0 = blockIdx.x * 64;
    const float4* nf4 = (const float4*)nf;
    const int base4 = n0 * (NIN / 4);
    for (int i = tid; i < 64 * NIN / 4; i += 256) {
        float4 v = make_float4(0.f, 0.f, 0.f, 0.f);
        if (base4 + i < V_N * NIN / 4) v = nf4[base4 + i];
        ushort4 p;
        p.x = f2bf(v.x); p.y = f2bf(v.y); p.z = f2bf(v.z); p.w = f2bf(v.w);
        ((ushort4*)sx)[i] = p;
    }
    for (int i = tid; i < 64*HH; i += 256) {
        const int gi = n0*HH + i;
        sen[i] = (gi < V_N*HH) ? node_out[gi] : 0.f;
    }
    __syncthreads();

    // phase B: node_node tile = relu(nf @ w_n2n + b)  -> snn (bf16)
    for (int t = tid; t < 8 * HH; t += 256) {
        const int rt = t / HH, c = t - rt * HH;
        float a[8];
        #pragma unroll
        for (int j = 0; j < 8; ++j) a[j] = sb[c];
        const u16* xr = &sx[rt * 8 * NIN];
        for (int k = 0; k < NIN; ++k) {
            const float w = bf2f(swn[k*HH + c]);
            #pragma unroll
            for (int j = 0; j < 8; ++j) a[j] = fmaf(bf2f(xr[j*NIN + k]), w, a[j]);
        }
        #pragma unroll
        for (int j = 0; j < 8; ++j)
            snn[(rt*8 + j)*HH + c] = f2bf(fmaxf(a[j], 0.f));
    }
    __syncthreads();

    // phase C: new_node = relu(concat(snn, sen) @ wU + bU)
    for (int t = tid; t < 16 * HH; t += 256) {
        const int et = t / HH, c = t - et * HH;
        const int n = et * 4;
        float acc[4];
        #pragma unroll
        for (int j = 0; j < 4; ++j) acc[j] = sb[HH + c];
        for (int k = 0; k < HH; ++k) {
            const float w = bf2f(swu[k*HH + c]);
            #pragma unroll
            for (int j = 0; j < 4; ++j) acc[j] = fmaf(bf2f(snn[(n+j)*HH + k]), w, acc[j]);
        }
        for (int k = 0; k < HH; ++k) {
            const float w = bf2f(swu[(HH + k)*HH + c]);
            #pragma unroll
            for (int j = 0; j < 4; ++j) acc[j] = fmaf(sen[(n+j)*HH + k], w, acc[j]);
        }
        #pragma unroll
        for (int j = 0; j < 4; ++j) {
            const int r = n0 + n + j;
            if (r < V_N) node_out[(size_t)r*HH + c] = fmaxf(acc[j], 0.f);
        }
    }
}

extern "C" void kernel_launch(void* const* d_in, const int* in_sizes, int n_in,
                              void* d_out, int out_size, void* d_ws, size_t ws_size,
                              hipStream_t stream) {
    const float* nf    = (const float*)d_in[0];
    const float* ef    = (const float*)d_in[1];
    const int*   src   = (const int*)d_in[2];
    const int*   dst   = (const int*)d_in[3];
    const float* w_n2n = (const float*)d_in[4];  const float* b_n2n = (const float*)d_in[5];
    const float* w_e2n = (const float*)d_in[6];  const float* b_e2n = (const float*)d_in[7];
    const float* w_updn= (const float*)d_in[8];  const float* b_updn= (const float*)d_in[9];
    const float* w_l   = (const float*)d_in[10]; const float* b_l   = (const float*)d_in[11];
    const float* w_r   = (const float*)d_in[12]; const float* b_r   = (const float*)d_in[13];
    const float* w_e2e = (const float*)d_in[14]; const float* b_e2e = (const float*)d_in[15];
    const float* w_upde= (const float*)d_in[16]; const float* b_upde= (const float*)d_in[17];

    // workspace layout (20 MB total — was 50 MB, which likely overran ws_size):
    //   [0,10MB)   left  bf16 (V x 50)
    //   [10,20MB)  right bf16 (V x 50)
    char* ws = (char*)d_ws;
    u16* left  = (u16*)ws;
    u16* right = (u16*)(ws + 10000000);

    float* out_node = (float*)d_out;                   // doubles as edge_node fp32 accumulator
    float* out_edge = out_node + (size_t)V_N * HH;

    hipMemsetAsync(out_node, 0, (size_t)V_N * HH * sizeof(float), stream);

    k_lr<<<(V_N + 63)/64, 256, 0, stream>>>(nf, w_l, b_l, w_r, b_r, left, right);

    k_edge<<<E_N/64, 256, 0, stream>>>(
        ef, src, dst, w_e2n, b_e2n, w_e2e, b_e2e, w_upde, b_upde,
        left, right, out_node, out_edge);

    k_node_upd<<<(V_N + 63)/64, 256, 0, stream>>>(
        nf, w_n2n, b_n2n, w_updn, b_updn, out_node);
}